// Round 6
// baseline (6773.508 us; speedup 1.0000x reference)
//
#include <hip/hip_runtime.h>

#define LSEQ 2048
#define TAGS 12

typedef _Float16 half2v __attribute__((ext_vector_type(2)));

__device__ __forceinline__ float sigm(float x){ return 1.0f/(1.0f+__expf(-x)); }
__device__ __forceinline__ float tanh_fast(float x){ return 1.0f - 2.0f/(1.0f+__expf(2.0f*x)); }
__device__ __forceinline__ half2v pack2(float a, float b){
  half2v r; r.x=(_Float16)a; r.y=(_Float16)b; return r;
}

// K1: xg[d][t][row] = b_ih[row]+b_hh[row] + sum_e embed[sent[t]][e] * w_ih[row][e]
__global__ void xg_kernel(
    const int* sent, const float* embed,
    const float* w_ih_f, const float* b_ih_f, const float* b_hh_f,
    const float* w_ih_b, const float* b_ih_b, const float* b_hh_b,
    float* xg)
{
  __shared__ float x_sh[8][256];
  int tid = threadIdx.x;
  int t0 = blockIdx.x * 8;
  for (int i=0;i<8;++i){
    int idx = sent[t0+i];
    x_sh[i][tid] = embed[(size_t)idx*256 + tid];
  }
  __syncthreads();
  for (int ri=0; ri<8; ++ri){
    int r = ri*256 + tid;
    int d = r >> 10;
    int row = r & 1023;
    const float* wr = (d ? w_ih_b : w_ih_f) + (size_t)row*256;
    const float* bi = d ? b_ih_b : b_ih_f;
    const float* bh = d ? b_hh_b : b_hh_f;
    float acc[8];
    #pragma unroll
    for (int i=0;i<8;++i) acc[i]=0.f;
    for (int k0=0;k0<256;k0+=4){
      float4 p = *(const float4*)(wr + k0);
      #pragma unroll
      for (int i=0;i<8;++i){
        acc[i] += p.x*x_sh[i][k0] + p.y*x_sh[i][k0+1]
                + p.z*x_sh[i][k0+2] + p.w*x_sh[i][k0+3];
      }
    }
    float bias = bi[row] + bh[row];
    #pragma unroll
    for (int i=0;i<8;++i)
      xg[((size_t)d*LSEQ + (size_t)(t0+i))*1024 + row] = acc[i] + bias;
  }
}

// K2: bidirectional LSTM recurrence — ONE CU per direction, no cross-CU traffic.
// Block d (512 threads, 8 waves): thread i owns gate rows i and 512+i
// (rows 0..511 = gates i,f; rows 512..1023 = gates g,o; PyTorch order).
// Weights f16-packed in VGPR/AGPR (256 regs). h state: f16 pairs in LDS,
// broadcast per wave via 2 ds_read_b32 + 128 v_readlane; dot via v_dot2_f32_f16.
// h history buffered in LDS, flushed to global (f16) every 16 steps.
__global__ __launch_bounds__(512,1) void lstm_rec(
    const float* __restrict__ w_hh_f, const float* __restrict__ w_hh_b,
    const float* __restrict__ xg, unsigned short* __restrict__ hstH)
{
  int d = blockIdx.x;
  int tid = threadIdx.x;
  int l = tid & 63;
  int r0 = tid, r1 = 512 + tid;
  const float* W = d ? w_hh_b : w_hh_f;
  const float* xgd = xg + (size_t)d*LSEQ*1024;
  unsigned short* hd = hstH + (size_t)d*LSEQ*256;

  __shared__ float gate_sh[1024];
  __shared__ unsigned short h16[256];
  __shared__ unsigned short hbuf[16][256];

  half2v w0[128], w1[128];
  {
    const float* a = W + (size_t)r0*256;
    const float* b = W + (size_t)r1*256;
    #pragma unroll
    for (int k0=0;k0<64;++k0){
      float4 p = *(const float4*)(a + 4*k0);
      w0[2*k0]   = pack2(p.x,p.y);
      w0[2*k0+1] = pack2(p.z,p.w);
      float4 q = *(const float4*)(b + 4*k0);
      w1[2*k0]   = pack2(q.x,q.y);
      w1[2*k0+1] = pack2(q.z,q.w);
    }
  }
  if (tid < 128) ((unsigned*)h16)[tid] = 0u;
  float c = 0.f;
  __syncthreads();

  int tf = d ? (LSEQ-1) : 0;
  float xg0 = xgd[(size_t)tf*1024 + r0];
  float xg1 = xgd[(size_t)tf*1024 + r1];

  for (int s=0;s<LSEQ;++s){
    const unsigned* h2 = (const unsigned*)h16;
    unsigned ha = h2[l];
    unsigned hb = h2[64+l];
    // prefetch next step's xg early so the dot issue hides the load
    float nxg0 = 0.f, nxg1 = 0.f;
    if (s+1 < LSEQ){
      int tn = d ? (LSEQ-2-s) : (s+1);
      nxg0 = xgd[(size_t)tn*1024 + r0];
      nxg1 = xgd[(size_t)tn*1024 + r1];
    }
    float a0=xg0, b0=0.f, a1=xg1, b1=0.f;
    #pragma unroll
    for (int k=0;k<64;k+=2){
      unsigned pa = __builtin_amdgcn_readlane(ha,k);
      unsigned pb = __builtin_amdgcn_readlane(ha,k+1);
      half2v va = __builtin_bit_cast(half2v,pa);
      half2v vb = __builtin_bit_cast(half2v,pb);
      a0 = __builtin_amdgcn_fdot2(va, w0[k],   a0, false);
      a1 = __builtin_amdgcn_fdot2(va, w1[k],   a1, false);
      b0 = __builtin_amdgcn_fdot2(vb, w0[k+1], b0, false);
      b1 = __builtin_amdgcn_fdot2(vb, w1[k+1], b1, false);
    }
    #pragma unroll
    for (int k=0;k<64;k+=2){
      unsigned pa = __builtin_amdgcn_readlane(hb,k);
      unsigned pb = __builtin_amdgcn_readlane(hb,k+1);
      half2v va = __builtin_bit_cast(half2v,pa);
      half2v vb = __builtin_bit_cast(half2v,pb);
      a0 = __builtin_amdgcn_fdot2(va, w0[64+k],   a0, false);
      a1 = __builtin_amdgcn_fdot2(va, w1[64+k],   a1, false);
      b0 = __builtin_amdgcn_fdot2(vb, w0[64+k+1], b0, false);
      b1 = __builtin_amdgcn_fdot2(vb, w1[64+k+1], b1, false);
    }
    float pre0 = a0 + b0;
    float pre1 = a1 + b1;
    xg0 = nxg0; xg1 = nxg1;
    float act0 = sigm(pre0);                                   // rows 0..511: i,f
    float act1 = (tid<256) ? tanh_fast(pre1) : sigm(pre1);     // rows 512..1023: g,o
    gate_sh[tid]       = act0;
    gate_sh[512 + tid] = act1;
    __syncthreads();
    if (tid < 256){
      float gi = gate_sh[tid];
      float gf = gate_sh[256+tid];
      float gg = gate_sh[512+tid];
      float go = gate_sh[768+tid];
      c = gf*c + gi*gg;
      float h = go * tanh_fast(c);
      _Float16 hh = (_Float16)h;
      unsigned short hu = __builtin_bit_cast(unsigned short, hh);
      h16[tid] = hu;
      hbuf[s&15][tid] = hu;
    }
    __syncthreads();
    if ((s&15)==15){
      // flush 16 steps of h history: thread tid stores 8 contiguous f16
      int q  = tid >> 5;            // which of the 16 buffered steps
      int u0 = (tid & 31) * 8;      // unit offset
      int ss = s - 15 + q;
      int tq = d ? (LSEQ-1-ss) : ss;
      uint4 v = *(const uint4*)&hbuf[q][u0];
      *(uint4*)&hd[(size_t)tq*256 + u0] = v;
    }
  }
}

// K3: feats[t][tag] = b_out[tag] + [hf|hb] . w_out[tag]   (h history is f16)
__global__ void feats_kernel(
    const unsigned short* hstH, const float* w_out, const float* b_out,
    float* feats)
{
  __shared__ float w_sh[12*520];
  __shared__ float h_sh[16*520];
  const _Float16* hf = (const _Float16*)hstH;
  int tid=threadIdx.x;
  int t0=blockIdx.x*16;
  for (int i=tid;i<12*512;i+=256){ int tag=i>>9,k=i&511; w_sh[tag*520+k]=w_out[i]; }
  for (int i=tid;i<16*512;i+=256){
    int tt=i>>9,k=i&511;
    float v = (k<256)? (float)hf[(size_t)(t0+tt)*256+k]
                     : (float)hf[(size_t)(LSEQ+t0+tt)*256 + (k-256)];
    h_sh[tt*520+k]=v;
  }
  __syncthreads();
  if (tid<192){
    int tt=tid/12, tag=tid%12;
    const float* wr=&w_sh[tag*520];
    const float* hr=&h_sh[tt*520];
    float acc=b_out[tag];
    for (int k=0;k<512;k+=4){
      float4 a=*(const float4*)(wr+k);
      float4 b=*(const float4*)(hr+k);
      acc += a.x*b.x+a.y*b.y+a.z*b.z+a.w*b.w;
    }
    feats[(size_t)(t0+tt)*12+tag]=acc;
  }
}

// K4: Viterbi DP: feats staged in LDS, v broadcast via readlane (register-resident),
// then parallel block-composed backtrack.
__global__ void BiLSTM_CRF_14405320311361_kernel(
    const float* feats, const float* trans, float* outp)
{
  __shared__ float fsh[LSEQ*12];           // 96 KB
  __shared__ unsigned char bps[LSEQ*12];   // 24 KB
  __shared__ float term_sh[16];
  __shared__ int ibuf[66];
  __shared__ unsigned char fmap[64*12];
  int tid = threadIdx.x;
  // stage feats into LDS (24576 floats)
  for (int i=tid; i<LSEQ*12/4; i+=256)
    *(float4*)&fsh[4*i] = *(const float4*)&feats[4*i];
  __syncthreads();

  int lane = tid & 63;
  int fl = (lane<12) ? lane : 0;
  float vn = 0.f;
  if (tid < 64){
    float tr[12];
    int next = fl;
    #pragma unroll
    for (int p=0;p<12;++p) tr[p] = trans[next*12+p];
    vn = (lane==10) ? 0.f : -10000.f;     // START=10
    float fa = fsh[fl];
    float fb = fsh[12+fl];
    for (int t=0;t<LSEQ;++t){
      unsigned vu = __float_as_uint(vn);
      float best; int bp; float sc;
      best = tr[0] + __uint_as_float(__builtin_amdgcn_readlane(vu,0)); bp = 0;
      sc = tr[1]  + __uint_as_float(__builtin_amdgcn_readlane(vu,1));  if(sc>best){best=sc;bp=1;}
      sc = tr[2]  + __uint_as_float(__builtin_amdgcn_readlane(vu,2));  if(sc>best){best=sc;bp=2;}
      sc = tr[3]  + __uint_as_float(__builtin_amdgcn_readlane(vu,3));  if(sc>best){best=sc;bp=3;}
      sc = tr[4]  + __uint_as_float(__builtin_amdgcn_readlane(vu,4));  if(sc>best){best=sc;bp=4;}
      sc = tr[5]  + __uint_as_float(__builtin_amdgcn_readlane(vu,5));  if(sc>best){best=sc;bp=5;}
      sc = tr[6]  + __uint_as_float(__builtin_amdgcn_readlane(vu,6));  if(sc>best){best=sc;bp=6;}
      sc = tr[7]  + __uint_as_float(__builtin_amdgcn_readlane(vu,7));  if(sc>best){best=sc;bp=7;}
      sc = tr[8]  + __uint_as_float(__builtin_amdgcn_readlane(vu,8));  if(sc>best){best=sc;bp=8;}
      sc = tr[9]  + __uint_as_float(__builtin_amdgcn_readlane(vu,9));  if(sc>best){best=sc;bp=9;}
      sc = tr[10] + __uint_as_float(__builtin_amdgcn_readlane(vu,10)); if(sc>best){best=sc;bp=10;}
      sc = tr[11] + __uint_as_float(__builtin_amdgcn_readlane(vu,11)); if(sc>best){best=sc;bp=11;}
      vn = best + fa;
      fa = fb;
      if (t+2 < LSEQ) fb = fsh[(t+2)*12+fl];
      if (lane<12) bps[t*12+lane] = (unsigned char)bp;
    }
  }
  if (tid < 12) term_sh[tid] = vn + trans[11*12+tid];   // STOP=11
  __syncthreads();
  if (tid == 0){
    float bs=term_sh[0]; int bt=0;
    for (int p=1;p<12;++p){ if (term_sh[p]>bs){bs=term_sh[p];bt=p;} }
    outp[0] = bs;
    ibuf[64] = bt;
  }
  __syncthreads();
  // B1: compose 32-step backpointer maps (64 blocks, one per thread of wave 0)
  if (tid < 64){
    int b = tid;
    int f[12];
    int thi = b*32+31;
    #pragma unroll
    for (int x=0;x<12;++x) f[x] = bps[thi*12+x];
    for (int t=thi-1; t>=b*32; --t){
      int base = t*12;
      #pragma unroll
      for (int x=0;x<12;++x) f[x] = bps[base + f[x]];
    }
    #pragma unroll
    for (int x=0;x<12;++x) fmap[b*12+x] = (unsigned char)f[x];
  }
  __syncthreads();
  // B2: chain across the 64 blocks
  if (tid == 0){
    int tag = ibuf[64];
    for (int b=63;b>=0;--b){ ibuf[b]=tag; tag = fmap[b*12+tag]; }
  }
  __syncthreads();
  // B3: re-walk blocks in parallel, emitting tags
  if (tid < 64){
    int b = tid;
    int tag = ibuf[b];
    for (int t=b*32+31; t>=b*32; --t){
      outp[1+t] = (float)tag;
      tag = bps[t*12+tag];
    }
  }
}

extern "C" void kernel_launch(void* const* d_in, const int* in_sizes, int n_in,
                              void* d_out, int out_size, void* d_ws, size_t ws_size,
                              hipStream_t stream) {
  const int*   sent   = (const int*)d_in[0];
  const float* embed  = (const float*)d_in[1];
  const float* w_ih_f = (const float*)d_in[2];
  const float* w_hh_f = (const float*)d_in[3];
  const float* b_ih_f = (const float*)d_in[4];
  const float* b_hh_f = (const float*)d_in[5];
  const float* w_ih_b = (const float*)d_in[6];
  const float* w_hh_b = (const float*)d_in[7];
  const float* b_ih_b = (const float*)d_in[8];
  const float* b_hh_b = (const float*)d_in[9];
  const float* w_out  = (const float*)d_in[10];
  const float* b_out  = (const float*)d_in[11];
  const float* trans  = (const float*)d_in[12];

  float* xg = (float*)d_ws;                                        // [2][L][1024] f32 = 16 MB
  unsigned short* hstH = (unsigned short*)(xg + (size_t)2*LSEQ*1024); // [2][L][256] f16 = 2 MB
  float* feats = (float*)(hstH + (size_t)2*LSEQ*256);              // [L][12] f32 = 96 KB
  float* outp  = (float*)d_out;

  xg_kernel<<<dim3(LSEQ/8), dim3(256), 0, stream>>>(
      sent, embed, w_ih_f, b_ih_f, b_hh_f, w_ih_b, b_ih_b, b_hh_b, xg);
  lstm_rec<<<dim3(2), dim3(512), 0, stream>>>(w_hh_f, w_hh_b, xg, hstH);
  feats_kernel<<<dim3(LSEQ/16), dim3(256), 0, stream>>>(hstH, w_out, b_out, feats);
  BiLSTM_CRF_14405320311361_kernel<<<dim3(1), dim3(256), 0, stream>>>(feats, trans, outp);
}